// Round 5
// baseline (241.819 us; speedup 1.0000x reference)
//
#include <hip/hip_runtime.h>
#include <hip/hip_bf16.h>

#define NFEAT 50
#define EDIM 64
#define LN_EPS 1e-5f
#define NEG_INF_C (-1000000000.0f)
#define NB 4

typedef __bf16 bf16_t;
typedef __bf16 bf16x8 __attribute__((ext_vector_type(8)));
typedef __bf16 bf16x4 __attribute__((ext_vector_type(4)));
typedef float f32x4 __attribute__((ext_vector_type(4)));

#define MFMA __builtin_amdgcn_mfma_f32_16x16x32_bf16

// ws layout:
//   attnT: bf16 [T][64][64], attnT[t][g][f] = attn[t][f][g], zero padded
//   WT:    bf16 [T][2][64][64] XOR-SWIZZLED (chunk c at row e holds k=(c^(e&7))*8+j)
//   tbT:   f32  [T][64][64], tbT[t][e][f] = tb[t][f][e], zero padded
//   attnF: f32  [T][64][64], attnF[t][f][g] = attn[t][f][g], zero padded
//   G:     f32  [T][64][64], G[t][f][k] s.t. gate logit_t = <F_b, G_t> + cst_t + gb
//   cst:   f32  [T]

__global__ __launch_bounds__(256) void prep_kernel(
    const float* __restrict__ masker, const float* __restrict__ ln_w,
    const float* __restrict__ ln_b, const float* __restrict__ tw,
    const float* __restrict__ tb, const float* __restrict__ gw,
    bf16_t* __restrict__ ws_attnT, bf16_t* __restrict__ ws_WT,
    float* __restrict__ ws_tbT, float* __restrict__ ws_attnF,
    float* __restrict__ ws_cst)
{
  __shared__ float red[2][4];
  const int tid = threadIdx.x;
  const int lane = tid & 63;
  const int gidx = blockIdx.x * 256 + tid;   // 0..4095

  // ---- WT staging (swizzled): 16384 elems, 4/thread ----
#pragma unroll
  for (int j = 0; j < 4; ++j) {
    int o = gidx * 4 + j;            // ((ti*64 + e)*64 + kl)
    int kl = o & 63;
    int e = (o >> 6) & 63;
    int ti = o >> 12;
    int k = ((kl >> 3) ^ (e & 7)) * 8 + (kl & 7);
    ws_WT[o] = (bf16_t)tw[(ti * 64 + k) * 64 + e];
  }

  // ---- tbT staging: 8192 elems, 2/thread ----
#pragma unroll
  for (int j = 0; j < 2; ++j) {
    int o = gidx * 2 + j;            // (t*64 + e)*64 + f
    int f = o & 63;
    int e = (o >> 6) & 63;
    int t = o >> 12;
    ws_tbT[o] = (f < NFEAT) ? tb[(t * NFEAT + f) * EDIM + e] : 0.f;
  }

  // ---- gate-bias constants: cst[t] = sum tb_t * gw (block 0 only) ----
  if (blockIdx.x == 0) {
    float s0 = 0.f, s1 = 0.f;
    for (int i = tid; i < NFEAT * EDIM; i += 256) {
      float g = gw[i];
      s0 += tb[i] * g;
      s1 += tb[NFEAT * EDIM + i] * g;
    }
    for (int off = 32; off > 0; off >>= 1) {
      s0 += __shfl_xor(s0, off);
      s1 += __shfl_xor(s1, off);
    }
    if (lane == 0) { red[0][tid >> 6] = s0; red[1][tid >> 6] = s1; }
    __syncthreads();
    if (tid == 0) {
      ws_cst[0] = red[0][0] + red[0][1] + red[0][2] + red[0][3];
      ws_cst[1] = red[1][0] + red[1][1] + red[1][2] + red[1][3];
    }
  }

  // ---- attention columns: 128 tasks (t,g) over 64 waves, 2 each ----
  const int wg = blockIdx.x * 4 + (tid >> 6);  // 0..63
  const int f = lane;
  const bool fv = (f < NFEAT);
  for (int i = 0; i < 2; ++i) {
    int col = wg * 2 + i;            // 0..127
    int t = col >> 6, g = col & 63;
    float val = 0.f;
    if (fv && g < NFEAT) {
      float a0 = masker[((t * 3 + 0) * NFEAT + f) * NFEAT + g];
      float a1 = masker[((t * 3 + 1) * NFEAT + f) * NFEAT + g];
      float a2 = masker[((t * 3 + 2) * NFEAT + f) * NFEAT + g];
      float prod = a0 * a1 * a2;
      val = prod > 0.f ? prod : 0.f;            // relu
    }
    float s = val;
    for (int off = 32; off > 0; off >>= 1) s += __shfl_xor(s, off);
    float mean = s / (float)NFEAT;
    float d = fv ? (val - mean) : 0.f;
    float v2 = d * d;
    for (int off = 32; off > 0; off >>= 1) v2 += __shfl_xor(v2, off);
    float var = v2 / (float)NFEAT;
    float lw = fv ? ln_w[f] : 0.f;
    float lb = fv ? ln_b[f] : 0.f;
    float aln = d * rsqrtf(var + LN_EPS) * lw + lb;
    float logit = aln + ((val != 0.f) ? 0.f : NEG_INF_C) + ((f == g) ? 1.f : 0.f);
    if (!fv) logit = -3.0e38f;
    float mx = logit;
    for (int off = 32; off > 0; off >>= 1) mx = fmaxf(mx, __shfl_xor(mx, off));
    float ex = fv ? expf(logit - mx) : 0.f;
    float se = ex;
    for (int off = 32; off > 0; off >>= 1) se += __shfl_xor(se, off);
    float attn = (fv && g < NFEAT && val != 0.f) ? (ex / se) : 0.f;
    ws_attnT[(t * 64 + g) * 64 + f] = (bf16_t)attn;
    ws_attnF[(t * 64 + f) * 64 + g] = attn;    // f-major copy for prep2
  }
}

// prep2: G_t[f][k] = V + Y,  V[f,k]=sum_e gw[f,e]W1_t[k,e],
// Y[f,k]=sum_g attn_t[f,g]*R[g,k], R[g,k]=sum_e gw[g,e]W2_t[k,e].
// One block per t; same MFMA fragment patterns as main (verified layouts).
__global__ __launch_bounds__(256) void prep2_kernel(
    const float* __restrict__ tw, const float* __restrict__ gw,
    const float* __restrict__ ws_attnF, float* __restrict__ ws_G)
{
  __shared__ bf16_t sRT[64 * 72];   // R^T[k][g], pitch 72
  const int t = blockIdx.x;
  const int tid = threadIdx.x;
  const int w = tid >> 6;
  const int lane = tid & 63;
  const int l16 = lane & 15;
  const int lquad = lane >> 4;
  const int fr = w * 16 + l16;       // A-row for this lane
  const bool frv = (fr < NFEAT);

  // A-frags from gw rows fr
  bf16x8 ag[2];
#pragma unroll
  for (int kc = 0; kc < 2; ++kc) {
#pragma unroll
    for (int j = 0; j < 8; ++j) ag[kc][j] = (bf16_t)0.f;
    if (frv) {
      const float* p = gw + fr * 64 + kc * 32 + lquad * 8;
      const f32x4 r0 = *(const f32x4*)(p);
      const f32x4 r1 = *(const f32x4*)(p + 4);
#pragma unroll
      for (int j = 0; j < 4; ++j) { ag[kc][j] = (bf16_t)r0[j]; ag[kc][j+4] = (bf16_t)r1[j]; }
    }
  }

  // R pass: accR[g-rows fr][k cols] via B = W2_t rows from tw
  f32x4 accR[4];
#pragma unroll
  for (int n = 0; n < 4; ++n) accR[n] = (f32x4){0.f,0.f,0.f,0.f};
#pragma unroll
  for (int kc = 0; kc < 2; ++kc)
#pragma unroll
    for (int n = 0; n < 4; ++n) {
      const float* p = tw + ((2*t+1)*64 + n*16 + l16) * 64 + kc*32 + lquad*8;
      const f32x4 r0 = *(const f32x4*)(p);
      const f32x4 r1 = *(const f32x4*)(p + 4);
      bf16x8 bw;
#pragma unroll
      for (int j = 0; j < 4; ++j) { bw[j] = (bf16_t)r0[j]; bw[j+4] = (bf16_t)r1[j]; }
      accR[n] = MFMA(ag[kc], bw, accR[n], 0, 0, 0);
    }
  // write R^T (row k = n*16+l16, col g = w*16+lquad*4+r)
#pragma unroll
  for (int n = 0; n < 4; ++n) {
    bf16x4 pv;
    pv[0]=(bf16_t)accR[n][0]; pv[1]=(bf16_t)accR[n][1];
    pv[2]=(bf16_t)accR[n][2]; pv[3]=(bf16_t)accR[n][3];
    *(bf16x4*)&sRT[(n*16 + l16) * 72 + w*16 + lquad*4] = pv;
  }

  // V pass (independent of R): acc = gw @ W1_t^T
  f32x4 acc[4];
#pragma unroll
  for (int n = 0; n < 4; ++n) acc[n] = (f32x4){0.f,0.f,0.f,0.f};
#pragma unroll
  for (int kc = 0; kc < 2; ++kc)
#pragma unroll
    for (int n = 0; n < 4; ++n) {
      const float* p = tw + ((2*t)*64 + n*16 + l16) * 64 + kc*32 + lquad*8;
      const f32x4 r0 = *(const f32x4*)(p);
      const f32x4 r1 = *(const f32x4*)(p + 4);
      bf16x8 bw;
#pragma unroll
      for (int j = 0; j < 4; ++j) { bw[j] = (bf16_t)r0[j]; bw[j+4] = (bf16_t)r1[j]; }
      acc[n] = MFMA(ag[kc], bw, acc[n], 0, 0, 0);
    }

  __syncthreads();   // sRT ready

  // Y pass: A = attnF rows fr (elems g), B = R from sRT
  bf16x8 aa[2];
#pragma unroll
  for (int kc = 0; kc < 2; ++kc) {
    const float* p = ws_attnF + (t*64 + fr) * 64 + kc*32 + lquad*8;
    const f32x4 r0 = *(const f32x4*)(p);
    const f32x4 r1 = *(const f32x4*)(p + 4);
#pragma unroll
    for (int j = 0; j < 4; ++j) { aa[kc][j] = (bf16_t)r0[j]; aa[kc][j+4] = (bf16_t)r1[j]; }
  }
#pragma unroll
  for (int kc = 0; kc < 2; ++kc)
#pragma unroll
    for (int n = 0; n < 4; ++n) {
      const bf16x8 bp = *(const bf16x8*)(&sRT[(n*16 + l16) * 72 + kc*32 + lquad*8]);
      acc[n] = MFMA(aa[kc], bp, acc[n], 0, 0, 0);
    }

  // store G rows f = w*16+lquad*4+r, cols k = n*16+l16  (rows >=50 are 0)
#pragma unroll
  for (int n = 0; n < 4; ++n)
#pragma unroll
    for (int r = 0; r < 4; ++r)
      ws_G[t*4096 + (w*16 + lquad*4 + r) * 64 + n*16 + l16] = acc[n][r];
}

// Role-split main: 4 waves. w0,w1 = H-waves (rows 32w..32w+31, BOTH t):
//   pass1 reads only W1_t0/W1_t1 frags; pass2 attnT@P; combine+store.
// w2,w3 = P-waves (one t each, all 64 rows): pass1 F@W2_t -> sPT[t];
//   also compute the full gate logit <F,G_t> (P-waves own the gate).
// LDS traffic/batch: 96KB vs 176KB before. 2 barriers/batch, no VGPR cap.
__global__ __launch_bounds__(256) void main_kernel(
    const float* __restrict__ feat, const float* __restrict__ gb,
    const bf16_t* __restrict__ ws_attnT, const bf16_t* __restrict__ ws_WT,
    const float* __restrict__ ws_tbT, const float* __restrict__ ws_G,
    const float* __restrict__ ws_cst,
    float* __restrict__ out)
{
  __shared__ bf16_t sWT[4 * 64 * 64];  // 32 KB swizzled
  __shared__ bf16_t sPT[2][64 * 72];   // P^T[e][f] per t, pitch 72
  __shared__ float sLog[2];

  const int tid = threadIdx.x;
  const int w = tid >> 6;
  const int lane = tid & 63;
  const int l16 = lane & 15;
  const int lquad = lane >> 4;
  const bool isH = (w < 2);
  const int pt = w - 2;                // P-wave tensor index (valid if !isH)
  const int exl = l16 & 7;

  // ---- stage sWT (linear copy; ws_WT pre-swizzled) ----
#pragma unroll
  for (int it = 0; it < 8; ++it) {
    const int idx = it * 256 + tid;
    *(bf16x8*)&sWT[idx * 8] = *(const bf16x8*)(ws_WT + idx * 8);
  }

  // ---- H persistent attnT A-frags: [t][kc][mloc] ----
  bf16x8 aat[2][2][2];
  if (isH) {
#pragma unroll
    for (int t = 0; t < 2; ++t)
#pragma unroll
      for (int kc = 0; kc < 2; ++kc)
#pragma unroll
        for (int ml = 0; ml < 2; ++ml)
          aat[t][kc][ml] = *(const bf16x8*)(ws_attnT +
              (t*64 + w*32 + ml*16 + l16) * 64 + kc*32 + lquad*8);
  }

  const float cst0 = ws_cst[0], cst1 = ws_cst[1], gbv = gb[0];
  const int b0 = blockIdx.x * NB;
  const int nm = isH ? 2 : 4;
  const int fbase = isH ? w * 32 : 0;

  // ---- prefetch raw feat for ib=0 (invalid rows stay zero forever) ----
  f32x4 raw[16];
#pragma unroll
  for (int i = 0; i < 16; ++i) raw[i] = (f32x4){0.f,0.f,0.f,0.f};
  {
    const float* fb = feat + (long)b0 * (NFEAT * EDIM);
#pragma unroll
    for (int m = 0; m < 4; ++m)
      if (m < nm) {
        const int frow = fbase + m * 16 + l16;
        if (frow < NFEAT) {
          const float* p = fb + frow * 64 + lquad * 8;
          raw[m*4+0] = *(const f32x4*)(p);
          raw[m*4+1] = *(const f32x4*)(p + 4);
          raw[m*4+2] = *(const f32x4*)(p + 32);
          raw[m*4+3] = *(const f32x4*)(p + 36);
        }
      }
  }

  __syncthreads();   // sWT ready

#pragma unroll 1
  for (int ib = 0; ib < NB; ++ib) {
    const int b = b0 + ib;

    // ---- convert raw -> bf16 A-frags ----
    bf16x8 a[2][4];
#pragma unroll
    for (int kc = 0; kc < 2; ++kc)
#pragma unroll
      for (int m = 0; m < 4; ++m)
#pragma unroll
        for (int j = 0; j < 4; ++j) {
          a[kc][m][j]     = (bf16_t)raw[m*4 + kc*2][j];
          a[kc][m][j + 4] = (bf16_t)raw[m*4 + kc*2 + 1][j];
        }

    // ---- P-waves: full gate logit <F, G_t> (before pass1) ----
    if (!isH) {
      const float* gt = ws_G + pt * 4096;
      float p = 0.f;
#pragma unroll
      for (int m = 0; m < 4; ++m) {
        const float* gp = gt + (m*16 + l16) * 64 + lquad * 8;
        const f32x4 g0 = *(const f32x4*)(gp);
        const f32x4 g1 = *(const f32x4*)(gp + 4);
        const f32x4 g2 = *(const f32x4*)(gp + 32);
        const f32x4 g3 = *(const f32x4*)(gp + 36);
#pragma unroll
        for (int j = 0; j < 4; ++j)
          p += raw[m*4+0][j]*g0[j] + raw[m*4+1][j]*g1[j]
             + raw[m*4+2][j]*g2[j] + raw[m*4+3][j]*g3[j];
      }
#pragma unroll
      for (int off = 32; off > 0; off >>= 1) p += __shfl_xor(p, off);
      if (lane == 0) sLog[pt] = p;
    }

    // ---- pass 1 ----
    f32x4 acc[16];
#pragma unroll
    for (int i = 0; i < 16; ++i) acc[i] = (f32x4){0.f,0.f,0.f,0.f};

    if (isH) {
#pragma unroll
      for (int kc = 0; kc < 2; ++kc) {
        const int co = ((kc*4 + lquad) ^ exl) * 8;
#pragma unroll
        for (int n = 0; n < 4; ++n) {
          const int ro = (n*16 + l16) * 64 + co;
          const bf16x8 bw0 = *(const bf16x8*)(&sWT[0*4096 + ro]);  // t0 W1
          const bf16x8 bw1 = *(const bf16x8*)(&sWT[2*4096 + ro]);  // t1 W1
#pragma unroll
          for (int ml = 0; ml < 2; ++ml) {
            acc[ml*4 + n]     = MFMA(a[kc][ml], bw0, acc[ml*4 + n], 0, 0, 0);
            acc[(2+ml)*4 + n] = MFMA(a[kc][ml], bw1, acc[(2+ml)*4 + n], 0, 0, 0);
          }
        }
      }
    } else {
      const int ti = 2*pt + 1;
#pragma unroll
      for (int kc = 0; kc < 2; ++kc) {
        const int co = ((kc*4 + lquad) ^ exl) * 8;
#pragma unroll
        for (int n = 0; n < 4; ++n) {
          const bf16x8 bw = *(const bf16x8*)(&sWT[ti*4096 + (n*16 + l16)*64 + co]);
#pragma unroll
          for (int m = 0; m < 4; ++m)
            acc[m*4 + n] = MFMA(a[kc][m], bw, acc[m*4 + n], 0, 0, 0);
        }
      }
      // write full P^T tile for this t
#pragma unroll
      for (int m = 0; m < 4; ++m)
#pragma unroll
        for (int n = 0; n < 4; ++n) {
          bf16x4 pv;
          pv[0]=(bf16_t)acc[m*4+n][0]; pv[1]=(bf16_t)acc[m*4+n][1];
          pv[2]=(bf16_t)acc[m*4+n][2]; pv[3]=(bf16_t)acc[m*4+n][3];
          *(bf16x4*)&sPT[pt][(n*16 + l16) * 72 + m*16 + lquad*4] = pv;
        }
    }

    __syncthreads();   // B1: sPT + sLog published

    // ---- prefetch next batch's raw (latency hides under pass2/store) ----
    if (ib + 1 < NB) {
      const float* fb = feat + (long)(b + 1) * (NFEAT * EDIM);
#pragma unroll
      for (int m = 0; m < 4; ++m)
        if (m < nm) {
          const int frow = fbase + m * 16 + l16;
          if (frow < NFEAT) {
            const float* p = fb + frow * 64 + lquad * 8;
            raw[m*4+0] = *(const f32x4*)(p);
            raw[m*4+1] = *(const f32x4*)(p + 4);
            raw[m*4+2] = *(const f32x4*)(p + 32);
            raw[m*4+3] = *(const f32x4*)(p + 36);
          }
        }
    }

    if (isH) {
      // gate softmax over T=2
      const float g0 = sLog[0] + cst0 + gbv;
      const float g1 = sLog[1] + cst1 + gbv;
      const float mx = fmaxf(g0, g1);
      const float e0 = expf(g0 - mx), e1 = expf(g1 - mx);
      const float inv = 1.f / (e0 + e1);
      const float ga0 = e0 * inv, ga1 = e1 * inv;

      // pass 2: acc[t][ml] += attnT_t @ P_t
#pragma unroll
      for (int kc = 0; kc < 2; ++kc)
#pragma unroll
        for (int n = 0; n < 4; ++n) {
          const int so = (n*16 + l16) * 72 + kc*32 + lquad*8;
          const bf16x8 bp0 = *(const bf16x8*)(&sPT[0][so]);
          const bf16x8 bp1 = *(const bf16x8*)(&sPT[1][so]);
#pragma unroll
          for (int ml = 0; ml < 2; ++ml) {
            acc[ml*4 + n]     = MFMA(aat[0][kc][ml], bp0, acc[ml*4 + n], 0, 0, 0);
            acc[(2+ml)*4 + n] = MFMA(aat[1][kc][ml], bp1, acc[(2+ml)*4 + n], 0, 0, 0);
          }
        }

      // combine + store
      float* outb = out + (long)b * (NFEAT * EDIM);
#pragma unroll
      for (int ml = 0; ml < 2; ++ml)
#pragma unroll
        for (int n = 0; n < 4; ++n) {
          const int fo = w*32 + ml*16 + lquad*4;
          const f32x4 tb0 = *(const f32x4*)(ws_tbT + (n*16 + l16)*64 + fo);
          const f32x4 tb1 = *(const f32x4*)(ws_tbT + 4096 + (n*16 + l16)*64 + fo);
          const int e = n*16 + l16;
#pragma unroll
          for (int r = 0; r < 4; ++r) {
            const int f = fo + r;
            if (f < NFEAT)
              outb[f*64 + e] = ga0 * (acc[ml*4 + n][r] + tb0[r])
                             + ga1 * (acc[(2+ml)*4 + n][r] + tb1[r]);
          }
        }
    }

    __syncthreads();   // B2: fences sPT/sLog reads before next iter's writes
  }
}

extern "C" void kernel_launch(void* const* d_in, const int* in_sizes, int n_in,
                              void* d_out, int out_size, void* d_ws, size_t ws_size,
                              hipStream_t stream) {
  const float* feat   = (const float*)d_in[0];
  const float* masker = (const float*)d_in[1];
  const float* tw     = (const float*)d_in[2];
  const float* tb     = (const float*)d_in[3];
  const float* lnw    = (const float*)d_in[4];
  const float* lnb    = (const float*)d_in[5];
  const float* gw     = (const float*)d_in[6];
  const float* gb     = (const float*)d_in[7];
  float* out = (float*)d_out;

  bf16_t* ws_attnT = (bf16_t*)d_ws;                  // 8192 bf16
  bf16_t* ws_WT    = ws_attnT + 8192;                // 16384 bf16
  float*  ws_tbT   = (float*)(ws_WT + 16384);        // 8192 f32
  float*  ws_attnF = ws_tbT + 8192;                  // 8192 f32
  float*  ws_G     = ws_attnF + 8192;                // 8192 f32
  float*  ws_cst   = ws_G + 8192;                    // 2 f32

  prep_kernel<<<16, 256, 0, stream>>>(masker, lnw, lnb, tw, tb, gw,
                                      ws_attnT, ws_WT, ws_tbT, ws_attnF, ws_cst);
  prep2_kernel<<<2, 256, 0, stream>>>(tw, gw, ws_attnF, ws_G);
  main_kernel<<<4096 / NB, 256, 0, stream>>>(feat, gb, ws_attnT, ws_WT,
                                             ws_tbT, ws_G, ws_cst, out);
}

// Round 6
// 140.676 us; speedup vs baseline: 1.7190x; 1.7190x over previous
//
#include <hip/hip_runtime.h>
#include <hip/hip_bf16.h>

#define NFEAT 50
#define EDIM 64
#define LN_EPS 1e-5f
#define NEG_INF_C (-1000000000.0f)
#define NB 4

typedef __bf16 bf16_t;
typedef __bf16 bf16x8 __attribute__((ext_vector_type(8)));
typedef __bf16 bf16x4 __attribute__((ext_vector_type(4)));
typedef float f32x4 __attribute__((ext_vector_type(4)));

#define MFMA __builtin_amdgcn_mfma_f32_16x16x32_bf16

// ws layout:
//   attnT: bf16 [T][64][64], attnT[t][g][f] = attn[t][f][g], zero padded
//   WT:    bf16 [T][2][64][64] XOR-SWIZZLED (chunk c at row e holds k=(c^(e&7))*8+j)
//   tbT:   f32  [T][64][64], tbT[t][e][f] = tb[t][f][e], zero padded
//   gwT:   f32  [64][64],    gwT[e][f]    = gw[f][e],    zero padded
//   cst:   f32  [T],         cst[t] = sum_{f,e} tb[t][f][e]*gw[f][e]

__global__ __launch_bounds__(256) void prep_kernel(
    const float* __restrict__ masker, const float* __restrict__ ln_w,
    const float* __restrict__ ln_b, const float* __restrict__ tw,
    const float* __restrict__ tb, const float* __restrict__ gw,
    bf16_t* __restrict__ ws_attnT, bf16_t* __restrict__ ws_WT,
    float* __restrict__ ws_tbT, float* __restrict__ ws_gwT,
    float* __restrict__ ws_cst)
{
  __shared__ float red[2][4];
  const int tid = threadIdx.x;
  const int lane = tid & 63;
  const int gidx = blockIdx.x * 256 + tid;   // 0..4095

  // ---- WT staging (swizzled): 16384 elems, 4/thread ----
#pragma unroll
  for (int j = 0; j < 4; ++j) {
    int o = gidx * 4 + j;            // ((ti*64 + e)*64 + kl)
    int kl = o & 63;
    int e = (o >> 6) & 63;
    int ti = o >> 12;
    int k = ((kl >> 3) ^ (e & 7)) * 8 + (kl & 7);
    ws_WT[o] = (bf16_t)tw[(ti * 64 + k) * 64 + e];
  }

  // ---- tbT staging: 8192 elems, 2/thread ----
#pragma unroll
  for (int j = 0; j < 2; ++j) {
    int o = gidx * 2 + j;            // (t*64 + e)*64 + f
    int f = o & 63;
    int e = (o >> 6) & 63;
    int t = o >> 12;
    ws_tbT[o] = (f < NFEAT) ? tb[(t * NFEAT + f) * EDIM + e] : 0.f;
  }

  // ---- gwT staging: 4096 elems, 1/thread ----
  {
    int o = gidx;                    // e*64 + f
    int f = o & 63;
    int e = o >> 6;
    ws_gwT[o] = (f < NFEAT) ? gw[f * EDIM + e] : 0.f;
  }

  // ---- gate-bias constants: cst[t] = sum tb_t * gw (block 0 only) ----
  if (blockIdx.x == 0) {
    float s0 = 0.f, s1 = 0.f;
    for (int i = tid; i < NFEAT * EDIM; i += 256) {
      float g = gw[i];
      s0 += tb[i] * g;
      s1 += tb[NFEAT * EDIM + i] * g;
    }
    for (int off = 32; off > 0; off >>= 1) {
      s0 += __shfl_xor(s0, off);
      s1 += __shfl_xor(s1, off);
    }
    if (lane == 0) { red[0][tid >> 6] = s0; red[1][tid >> 6] = s1; }
    __syncthreads();
    if (tid == 0) {
      ws_cst[0] = red[0][0] + red[0][1] + red[0][2] + red[0][3];
      ws_cst[1] = red[1][0] + red[1][1] + red[1][2] + red[1][3];
    }
  }

  // ---- attention columns: 128 tasks (t,g) over 64 waves, 2 each ----
  const int wg = blockIdx.x * 4 + (tid >> 6);  // 0..63
  const int f = lane;
  const bool fv = (f < NFEAT);
  for (int i = 0; i < 2; ++i) {
    int col = wg * 2 + i;            // 0..127
    int t = col >> 6, g = col & 63;
    float val = 0.f;
    if (fv && g < NFEAT) {
      float a0 = masker[((t * 3 + 0) * NFEAT + f) * NFEAT + g];
      float a1 = masker[((t * 3 + 1) * NFEAT + f) * NFEAT + g];
      float a2 = masker[((t * 3 + 2) * NFEAT + f) * NFEAT + g];
      float prod = a0 * a1 * a2;
      val = prod > 0.f ? prod : 0.f;            // relu
    }
    float s = val;
    for (int off = 32; off > 0; off >>= 1) s += __shfl_xor(s, off);
    float mean = s / (float)NFEAT;
    float d = fv ? (val - mean) : 0.f;
    float v2 = d * d;
    for (int off = 32; off > 0; off >>= 1) v2 += __shfl_xor(v2, off);
    float var = v2 / (float)NFEAT;
    float lw = fv ? ln_w[f] : 0.f;
    float lb = fv ? ln_b[f] : 0.f;
    float aln = d * rsqrtf(var + LN_EPS) * lw + lb;
    float logit = aln + ((val != 0.f) ? 0.f : NEG_INF_C) + ((f == g) ? 1.f : 0.f);
    if (!fv) logit = -3.0e38f;
    float mx = logit;
    for (int off = 32; off > 0; off >>= 1) mx = fmaxf(mx, __shfl_xor(mx, off));
    float ex = fv ? expf(logit - mx) : 0.f;
    float se = ex;
    for (int off = 32; off > 0; off >>= 1) se += __shfl_xor(se, off);
    float attn = (fv && g < NFEAT && val != 0.f) ? (ex / se) : 0.f;
    ws_attnT[(t * 64 + g) * 64 + f] = (bf16_t)attn;
  }
}

// R4 structure (champion): 256 threads, 4 symmetric waves, merged t, NB=4,
// no VGPR cap, sWT staged once per block. Round-6 deltas:
//  (1) sPT pitch 72 -> 64 with XOR chunk swizzle (same pattern as sWT):
//      kills the 8-way bank conflict on pass-2 reads (was all 1.57M cycles).
//  (2) next-batch feat prefetch moved AFTER B1: hides under pass2+reduce
//      (~600cy window) instead of pass1 only (~300cy) before B1's vmcnt(0).
__global__ __launch_bounds__(256) void main_kernel(
    const float* __restrict__ feat, const float* __restrict__ gb,
    const bf16_t* __restrict__ ws_attnT, const bf16_t* __restrict__ ws_WT,
    const float* __restrict__ ws_tbT, const float* __restrict__ ws_gwT,
    const float* __restrict__ ws_cst,
    float* __restrict__ out)
{
  __shared__ bf16_t sWT[4 * 64 * 64];  // 32 KB, swizzled [ti][e][chunk^e&7][8]
  __shared__ bf16_t sPT[2][64 * 64];   // 16 KB, swizzled P^T per t, pitch 64
  __shared__ float sLog[2][4];

  const int tid = threadIdx.x;
  const int w = tid >> 6;
  const int lane = tid & 63;
  const int l16 = lane & 15;
  const int lquad = lane >> 4;
  const int m0 = w * 16;

  // ---- stage WT into LDS (linear copy; global is pre-swizzled) ----
#pragma unroll
  for (int it = 0; it < 8; ++it) {
    const int idx = it * 256 + tid;    // 16B chunk id, 0..2047
    *(bf16x8*)&sWT[idx * 8] = *(const bf16x8*)(ws_WT + idx * 8);
  }

  // ---- block-invariant register state ----
  bf16x8 aat[2][2];                    // attnT A-frags (rows g = m0+l16)
#pragma unroll
  for (int t = 0; t < 2; ++t)
#pragma unroll
    for (int kc = 0; kc < 2; ++kc)
      aat[t][kc] = *(const bf16x8*)(ws_attnT + (t * 64 + m0 + l16) * 64 + kc * 32 + lquad * 8);

  const float cst0 = ws_cst[0], cst1 = ws_cst[1], gbv = gb[0];
  const int fA = m0 + l16;
  const bool fAv = (fA < NFEAT);
  const int b0 = blockIdx.x * NB;
  const int foff = fA * 64 + lquad * 8;
  const int exl = l16 & 7;             // e&7 for this lane (rows are n*16+l16)
  const int wcl = (m0 >> 3) + (lquad >> 1);   // logical f-chunk of this lane's P write
  const int whf = (lquad & 1) * 4;            // half-chunk element offset

  // ---- prefetch feat for ib = 0 ----
  f32x4 raw[4];
  if (fAv) {
    const float* fb = feat + b0 * (NFEAT * EDIM) + foff;
    raw[0] = *(const f32x4*)(fb);
    raw[1] = *(const f32x4*)(fb + 4);
    raw[2] = *(const f32x4*)(fb + 32);
    raw[3] = *(const f32x4*)(fb + 36);
  }

  __syncthreads();                     // sWT ready

#pragma unroll 1
  for (int ib = 0; ib < NB; ++ib) {
    const int b = b0 + ib;

    // ---- convert prefetched raw -> bf16 A-frags ----
    bf16x8 a[2];
#pragma unroll
    for (int kc = 0; kc < 2; ++kc)
#pragma unroll
      for (int j = 0; j < 8; ++j) a[kc][j] = (bf16_t)0.f;
    if (fAv) {
#pragma unroll
      for (int j = 0; j < 4; ++j) {
        a[0][j] = (bf16_t)raw[0][j]; a[0][j + 4] = (bf16_t)raw[1][j];
        a[1][j] = (bf16_t)raw[2][j]; a[1][j + 4] = (bf16_t)raw[3][j];
      }
    }

    f32x4 accH[2][4], accP[2][4];
#pragma unroll
    for (int t = 0; t < 2; ++t)
#pragma unroll
      for (int n = 0; n < 4; ++n) {
        accH[t][n] = (f32x4){0.f, 0.f, 0.f, 0.f};
        accP[t][n] = (f32x4){0.f, 0.f, 0.f, 0.f};
      }

    // ---- pass 1: B-frags from LDS (swizzled chunk), 4 indep MFMA streams ----
#pragma unroll
    for (int kc = 0; kc < 2; ++kc) {
      const int co = ((kc * 4 + lquad) ^ exl) * 8;
#pragma unroll
      for (int n = 0; n < 4; ++n) {
        const int ro = (n * 16 + l16) * 64 + co;
        const bf16x8 b10 = *(const bf16x8*)(&sWT[0 * 4096 + ro]);  // t0 W1
        const bf16x8 b20 = *(const bf16x8*)(&sWT[1 * 4096 + ro]);  // t0 W2
        const bf16x8 b11 = *(const bf16x8*)(&sWT[2 * 4096 + ro]);  // t1 W1
        const bf16x8 b21 = *(const bf16x8*)(&sWT[3 * 4096 + ro]);  // t1 W2
        accH[0][n] = MFMA(a[kc], b10, accH[0][n], 0, 0, 0);
        accP[0][n] = MFMA(a[kc], b20, accP[0][n], 0, 0, 0);
        accH[1][n] = MFMA(a[kc], b11, accH[1][n], 0, 0, 0);
        accP[1][n] = MFMA(a[kc], b21, accP[1][n], 0, 0, 0);
      }
    }

    // ---- write both P^T tiles to LDS (swizzled, pitch 64) ----
#pragma unroll
    for (int t = 0; t < 2; ++t)
#pragma unroll
      for (int n = 0; n < 4; ++n) {
        bf16x4 pv;
        pv[0] = (bf16_t)accP[t][n][0]; pv[1] = (bf16_t)accP[t][n][1];
        pv[2] = (bf16_t)accP[t][n][2]; pv[3] = (bf16_t)accP[t][n][3];
        *(bf16x4*)&sPT[t][(n * 16 + l16) * 64 + ((wcl ^ exl) << 3) + whf] = pv;
      }
    __syncthreads();   // BARRIER1: sPT ready

    // ---- prefetch next batch's feat (drains at B2; window = pass2+reduce) ----
    if (ib + 1 < NB && fAv) {
      const float* fb = feat + (b + 1) * (NFEAT * EDIM) + foff;
      raw[0] = *(const f32x4*)(fb);
      raw[1] = *(const f32x4*)(fb + 4);
      raw[2] = *(const f32x4*)(fb + 32);
      raw[3] = *(const f32x4*)(fb + 36);
    }

    // ---- pass 2: accH[t] += attnT_t @ P_t (swizzled conflict-free reads) ----
#pragma unroll
    for (int kc = 0; kc < 2; ++kc) {
      const int so0 = ((kc * 4 + lquad) ^ exl) << 3;
#pragma unroll
      for (int n = 0; n < 4; ++n) {
        const int so = (n * 16 + l16) * 64 + so0;
        const bf16x8 bp0 = *(const bf16x8*)(&sPT[0][so]);
        const bf16x8 bp1 = *(const bf16x8*)(&sPT[1][so]);
        accH[0][n] = MFMA(aat[0][kc], bp0, accH[0][n], 0, 0, 0);
        accH[1][n] = MFMA(aat[1][kc], bp1, accH[1][n], 0, 0, 0);
      }
    }

    // ---- gate-logit partials: p_t = sum accH_t * gw (tb folded into cst) ----
    float p0 = 0.f, p1 = 0.f;
#pragma unroll
    for (int n = 0; n < 4; ++n) {
      const f32x4 gwv = *(const f32x4*)(ws_gwT + (n * 16 + l16) * 64 + m0 + lquad * 4);
#pragma unroll
      for (int r = 0; r < 4; ++r) {
        p0 += accH[0][n][r] * gwv[r];
        p1 += accH[1][n][r] * gwv[r];
      }
    }
#pragma unroll
    for (int off = 32; off > 0; off >>= 1) {
      p0 += __shfl_xor(p0, off);
      p1 += __shfl_xor(p1, off);
    }
    if (lane == 0) { sLog[0][w] = p0; sLog[1][w] = p1; }
    __syncthreads();   // BARRIER2: sLog visible; fences sPT for next iter

    // ---- gate softmax over T=2, weighted sum (+tb at store), store ----
    const float g0 = sLog[0][0] + sLog[0][1] + sLog[0][2] + sLog[0][3] + cst0 + gbv;
    const float g1 = sLog[1][0] + sLog[1][1] + sLog[1][2] + sLog[1][3] + cst1 + gbv;
    const float mx = fmaxf(g0, g1);
    const float e0 = expf(g0 - mx), e1 = expf(g1 - mx);
    const float inv = 1.f / (e0 + e1);
    const float ga0 = e0 * inv, ga1 = e1 * inv;

    float* outb = out + b * (NFEAT * EDIM);
#pragma unroll
    for (int n = 0; n < 4; ++n) {
      const int ro = (n * 16 + l16) * 64 + m0 + lquad * 4;
      const f32x4 tbv0 = *(const f32x4*)(ws_tbT + ro);
      const f32x4 tbv1 = *(const f32x4*)(ws_tbT + 64 * 64 + ro);
      const int e = n * 16 + l16;
#pragma unroll
      for (int r = 0; r < 4; ++r) {
        const int f = m0 + lquad * 4 + r;
        if (f < NFEAT)
          outb[f * 64 + e] = ga0 * (accH[0][n][r] + tbv0[r])
                           + ga1 * (accH[1][n][r] + tbv1[r]);
      }
    }
  }
}

extern "C" void kernel_launch(void* const* d_in, const int* in_sizes, int n_in,
                              void* d_out, int out_size, void* d_ws, size_t ws_size,
                              hipStream_t stream) {
  const float* feat   = (const float*)d_in[0];
  const float* masker = (const float*)d_in[1];
  const float* tw     = (const float*)d_in[2];
  const float* tb     = (const float*)d_in[3];
  const float* lnw    = (const float*)d_in[4];
  const float* lnb    = (const float*)d_in[5];
  const float* gw     = (const float*)d_in[6];
  const float* gb     = (const float*)d_in[7];
  float* out = (float*)d_out;

  bf16_t* ws_attnT = (bf16_t*)d_ws;                 // 8192 bf16
  bf16_t* ws_WT    = ws_attnT + 2 * 64 * 64;        // 16384 bf16
  float*  ws_tbT   = (float*)(ws_WT + 4 * 64 * 64); // 8192 f32
  float*  ws_gwT   = ws_tbT + 2 * 64 * 64;          // 4096 f32
  float*  ws_cst   = ws_gwT + 64 * 64;              // 2 f32

  prep_kernel<<<16, 256, 0, stream>>>(masker, lnw, lnb, tw, tb, gw,
                                      ws_attnT, ws_WT, ws_tbT, ws_gwT, ws_cst);
  main_kernel<<<4096 / NB, 256, 0, stream>>>(feat, gb, ws_attnT, ws_WT,
                                             ws_tbT, ws_gwT, ws_cst, out);
}